// Round 11
// baseline (200.421 us; speedup 1.0000x reference)
//
#include <hip/hip_runtime.h>
#include <hip/hip_bf16.h>

// ---------------------------------------------------------------------------
// B=16, N=512, DIN=128, DH=256
// out = [node_logits 8192x8192 f32 | graph_logits 16x16 | div_loss]
// R11: G10 -> 256x256 tile, 512 threads (8 waves), halves n1/n2 re-read
// traffic (536->268 MB) and block count (4096->1024). Same 2-barrier m97
// staging, LDS-bounce nt-store epilogue, fused readout in block 0.
// Middle chain unchanged from R10 (direct-L2 fragments).
// ---------------------------------------------------------------------------

using bf16x8 = __attribute__((ext_vector_type(8))) short;
using f32x4  = __attribute__((ext_vector_type(4))) float;

__device__ __forceinline__ unsigned short f2b(float f) {
    union { float f; unsigned int u; } x; x.f = f;
    unsigned int r = x.u + 0x7FFFu + ((x.u >> 16) & 1u);   // RNE
    return (unsigned short)(r >> 16);
}
__device__ __forceinline__ void gload_lds16(const void* g, void* l) {
    __builtin_amdgcn_global_load_lds(
        (const __attribute__((address_space(1))) void*)g,
        (__attribute__((address_space(3))) void*)l, 16, 0, 0);
}
__device__ __forceinline__ bf16x8 ldfrag(const unsigned short* p) {
    return *reinterpret_cast<const bf16x8*>(p);
}

// ---------------- prep: conv3 + all 6 weight transposes ----------------
__global__ __launch_bounds__(256) void prep(
    const float* __restrict__ seq, const float* __restrict__ adj,
    const float* __restrict__ diff,
    const float* __restrict__ fc1, const float* __restrict__ fc2,
    const float* __restrict__ qw,  const float* __restrict__ kw,
    const float* __restrict__ v1,  const float* __restrict__ v2,
    unsigned short* __restrict__ seq_bf, unsigned short* __restrict__ adj_bf,
    unsigned short* __restrict__ diff_bf,
    unsigned short* fc1T, unsigned short* fc2T, unsigned short* qwT,
    unsigned short* kwT,  unsigned short* v1T,  unsigned short* v2T)
{
    __shared__ float t[32][33];
    const int bid = blockIdx.x, tid = threadIdx.x;
    if (bid < 9216) {
        long i = (long)bid * 256 + tid;   // quad index
        const float* src; unsigned short* dst; long off;
        if (i < 262144)       { src = seq;  dst = seq_bf;  off = i; }
        else if (i < 1310720) { src = adj;  dst = adj_bf;  off = i - 262144; }
        else                  { src = diff; dst = diff_bf; off = i - 1310720; }
        float4 v = reinterpret_cast<const float4*>(src)[off];
        ushort4 o; o.x = f2b(v.x); o.y = f2b(v.y); o.z = f2b(v.z); o.w = f2b(v.w);
        reinterpret_cast<ushort4*>(dst)[off] = o;
        return;
    }
    const int r = bid - 9216;
    const int z = r >> 6;
    const float* in; unsigned short* op; int R;
    if      (z == 0) { in = fc1; op = fc1T; R = 128; }
    else if (z == 1) { in = fc2; op = fc2T; R = 128; }
    else if (z == 2) { in = qw;  op = qwT;  R = 256; }
    else if (z == 3) { in = kw;  op = kwT;  R = 256; }
    else if (z == 4) { in = v1;  op = v1T;  R = 256; }
    else             { in = v2;  op = v2T;  R = 256; }
    const int c0 = (r & 7) * 32, r0 = ((r >> 3) & 7) * 32;
    if (r0 >= R) return;
    const int x = tid & 31, y = tid >> 5;
    for (int i = 0; i < 32; i += 8) t[y + i][x] = in[(long)(r0 + y + i) * 256 + c0 + x];
    __syncthreads();
    for (int i = 0; i < 32; i += 8)
        op[(long)(c0 + y + i) * R + r0 + x] = f2b(t[x][y + i]);
}

// ---------------- MFMA NT GEMM (m97 staging), 64 x 128 tile, BK=64 ----------------
#define BN 128
#define BK 64

__global__ __launch_bounds__(256) void gemm_small(
    const unsigned short* __restrict__ A, const unsigned short* __restrict__ Bt,
    unsigned short* __restrict__ Cb,
    int K, int lda, int ldb, int ldc, long sA, long sB, long sC)
{
    __shared__ unsigned short As[64 * BK];
    __shared__ unsigned short Bs[BN * BK];
    const int b = blockIdx.z;
    A  += (long)b * sA;
    Bt += (long)b * sB;
    const long cbase = (long)b * sC;
    const int tile_m = blockIdx.y * 64;
    const int tile_n = blockIdx.x * BN;

    const int tid  = threadIdx.x;
    const int lane = tid & 63;
    const int wave = tid >> 6;
    const int wm = (wave >> 1) * 32;
    const int wn = (wave & 1) << 6;
    const int lrow = lane >> 3;
    const int lcol = (lane & 7) << 3;

    f32x4 acc[2][4] = {};

    for (int k0 = 0; k0 < K; k0 += BK) {
        #pragma unroll
        for (int i = 0; i < 2; ++i) {
            const int rb = (i * 4 + wave) * 8;
            gload_lds16(A + (long)(tile_m + rb + lrow) * lda + k0 + lcol, &As[rb * BK]);
        }
        #pragma unroll
        for (int i = 0; i < 4; ++i) {
            const int rb = (i * 4 + wave) * 8;
            gload_lds16(Bt + (long)(tile_n + rb + lrow) * ldb + k0 + lcol, &Bs[rb * BK]);
        }
        __syncthreads();
        #pragma unroll
        for (int ks = 0; ks < 2; ++ks) {
            const int kk = ks * 32 + ((lane >> 4) << 3);
            bf16x8 af[2], bq[4];
            #pragma unroll
            for (int mi = 0; mi < 2; ++mi)
                af[mi] = ldfrag(&As[(wm + (lane & 15) + mi * 16) * BK + kk]);
            #pragma unroll
            for (int ni = 0; ni < 4; ++ni)
                bq[ni] = ldfrag(&Bs[(wn + (lane & 15) + ni * 16) * BK + kk]);
            #pragma unroll
            for (int mi = 0; mi < 2; ++mi)
                #pragma unroll
                for (int ni = 0; ni < 4; ++ni)
                    acc[mi][ni] = __builtin_amdgcn_mfma_f32_16x16x32_bf16(
                        af[mi], bq[ni], acc[mi][ni], 0, 0, 0);
        }
        __syncthreads();
    }

    const int c0 = lane & 15;
    const int r0 = (lane >> 4) << 2;
    #pragma unroll
    for (int ni = 0; ni < 4; ++ni) {
        const int col = tile_n + wn + ni * 16 + c0;
        #pragma unroll
        for (int mi = 0; mi < 2; ++mi) {
            const int row0 = tile_m + wm + mi * 16 + r0;
            #pragma unroll
            for (int j = 0; j < 4; ++j)
                Cb[cbase + (long)(row0 + j) * ldc + col] = f2b(acc[mi][ni][j]);
        }
    }
}

// ---------------- G10: 256x256 tile, 512 threads, fused readout ----------------
__global__ __launch_bounds__(512) void gemm_big(
    const unsigned short* __restrict__ A,   // n1 [8192][256]
    const unsigned short* __restrict__ Bt,  // n2 [8192][256]
    float* __restrict__ Cf,                 // out [8192][8192]
    const float* __restrict__ rd_psum1, const float* __restrict__ rd_psum2,
    const float* __restrict__ rd_rowpart,
    float* __restrict__ rd_outg, float* __restrict__ rd_outdiv)
{
    __shared__ unsigned char smem_g[65536];
    unsigned short* As = (unsigned short*)smem_g;            // [256][64]
    unsigned short* Bs = (unsigned short*)(smem_g + 32768);  // [256][64]
    __shared__ float rd_invn[32];
    __shared__ float rd_red[8];

    // bijective XCD swizzle over 1024 blocks
    const int bid = blockIdx.x;
    const int s = (bid & 7) * 128 + (bid >> 3);
    const int tx = s & 31, ty = s >> 5;
    const int tile_m = ty << 8, tile_n = tx << 8;

    const int tid  = threadIdx.x;
    const int lane = tid & 63;
    const int wave = tid >> 6;        // 0..7
    const int wr = wave >> 2;         // 0..1 (row half)
    const int wc = wave & 3;          // 0..3 (col quarter)
    const int lrow = lane >> 3;
    const int lcol = (lane & 7) << 3;
    const int hi = lane >> 4, c0 = lane & 15, r0 = hi << 2;

    f32x4 acc[8][4] = {};

    for (int k0 = 0; k0 < 256; k0 += 64) {
        #pragma unroll
        for (int i = 0; i < 4; ++i) {
            const int rb = (i * 8 + wave) * 8;
            gload_lds16(A  + (long)(tile_m + rb + lrow) * 256 + k0 + lcol, &As[rb * 64]);
            gload_lds16(Bt + (long)(tile_n + rb + lrow) * 256 + k0 + lcol, &Bs[rb * 64]);
        }
        __syncthreads();
        #pragma unroll
        for (int ks = 0; ks < 2; ++ks) {
            const int kk = ks * 32 + (hi << 3);
            bf16x8 af[8], bq[4];
            #pragma unroll
            for (int mi = 0; mi < 8; ++mi)
                af[mi] = ldfrag(&As[(wr * 128 + mi * 16 + c0) * 64 + kk]);
            #pragma unroll
            for (int ni = 0; ni < 4; ++ni)
                bq[ni] = ldfrag(&Bs[(wc * 64 + ni * 16 + c0) * 64 + kk]);
            #pragma unroll
            for (int mi = 0; mi < 8; ++mi)
                #pragma unroll
                for (int ni = 0; ni < 4; ++ni)
                    acc[mi][ni] = __builtin_amdgcn_mfma_f32_16x16x32_bf16(
                        af[mi], bq[ni], acc[mi][ni], 0, 0, 0);
        }
        __syncthreads();
    }

    // epilogue: 4 chunks of 64 rows; bounce 64x256 f32 through the 64KB LDS,
    // then fully-coalesced nontemporal f32x4 row stores (1KB per wave-inst).
    float* bounce = (float*)smem_g;
    const int tr8 = tid >> 6;          // 0..7
    const int tcc = (lane) << 2;       // f32 col base 0..252
    #pragma unroll
    for (int h = 0; h < 4; ++h) {
        __syncthreads();
        if (wr == (h >> 1)) {
            const int mib = (h & 1) * 4;
            #pragma unroll
            for (int mm = 0; mm < 4; ++mm)
                #pragma unroll
                for (int ni = 0; ni < 4; ++ni)
                    #pragma unroll
                    for (int j = 0; j < 4; ++j)
                        bounce[(mm * 16 + r0 + j) * 256 + wc * 64 + ni * 16 + c0] =
                            acc[mib + mm][ni][j];
        }
        __syncthreads();
        #pragma unroll
        for (int p = 0; p < 8; ++p) {
            const int rl = p * 8 + tr8;
            f32x4 v = *reinterpret_cast<const f32x4*>(&bounce[rl * 256 + tcc]);
            __builtin_nontemporal_store(v, reinterpret_cast<f32x4*>(
                &Cf[(long)(tile_m + h * 64 + rl) * 8192 + tile_n + tcc]));
        }
    }

    // fused readout (block 0 only; swizzle maps bid 0 -> tile (0,0))
    if (bid == 0) {
        __syncthreads();
        float* c1s = (float*)smem_g;          // [16][256]
        float* c2s = c1s + 4096;              // [16][256]
        const int t = tid & 255;
        const int half = tid >> 8;            // 0 -> psum1, 1 -> psum2
        const float* ps = half ? rd_psum2 : rd_psum1;
        float* cs = half ? c2s : c1s;
        for (int g = 0; g < 16; ++g) {
            float s1 = 0.f;
            #pragma unroll
            for (int c = 0; c < 16; ++c) s1 += ps[(long)(g * 16 + c) * 256 + t];
            cs[g * 256 + t] = s1 * (1.f / 512.f);
        }
        __syncthreads();
        if (tid < 32) {
            const float* row = (tid < 16) ? &c1s[tid * 256] : &c2s[(tid - 16) * 256];
            float ss = 0.f;
            for (int hh = 0; hh < 256; ++hh) { float v = row[hh]; ss += v * v; }
            rd_invn[tid] = 1.f / fmaxf(sqrtf(ss), 1e-12f);
        }
        __syncthreads();
        if (tid < 256) {
            const int ii = tid >> 4, jj = tid & 15;
            float s2 = 0.f;
            for (int hh = 0; hh < 256; ++hh) s2 += c1s[ii * 256 + hh] * c2s[jj * 256 + hh];
            rd_outg[ii * 16 + jj] = s2 * rd_invn[ii] * rd_invn[16 + jj];
        }
        float ds = 0.f;
        for (int i = tid; i < 8192; i += 512) ds += rd_rowpart[i];
        #pragma unroll
        for (int o = 32; o; o >>= 1) ds += __shfl_xor(ds, o);
        if (lane == 0) rd_red[wave] = ds;
        __syncthreads();
        if (tid == 0) {
            float tot = 0.f;
            #pragma unroll
            for (int w = 0; w < 8; ++w) tot += rd_red[w];
            rd_outdiv[0] = tot * (1.f / 8192.f);
        }
    }
}

// ---------------- gcn1qk: out=adj@fts (->outT+LDS Ot) then qk-proj + l2norm ----------------
__global__ __launch_bounds__(256) void gcn1qk(
    const unsigned short* __restrict__ adj_bf, // [16][512][512]
    const unsigned short* __restrict__ ftsT,   // [256][8192]
    const unsigned short* __restrict__ qkT,    // [512][256] stacked q|k
    unsigned short* __restrict__ outT,         // [16][256][512]
    unsigned short* __restrict__ q_bf,         // [16][512][256]
    unsigned short* __restrict__ k_bf)         // [16][512][256]
{
    __shared__ unsigned short Ot[16 * 264];
    __shared__ float sred[16][4];

    const int b  = blockIdx.y;
    const int m0 = blockIdx.x << 4;
    const int tid = threadIdx.x, lane = tid & 63, wave = tid >> 6;
    const int hi = lane >> 4, c0 = lane & 15, r0 = hi << 2;
    const int ko = hi << 3;   // fragment k-offset (elements)

    // ---- phase 1: out[16][256] = adj[16,512] @ fts[512,256]  (direct) ----
    {
        const int wn = wave << 6;
        const unsigned short* ap = adj_bf + ((long)b * 512 + m0 + c0) * 512;
        f32x4 acc[4] = {};
        #pragma unroll 2
        for (int k0 = 0; k0 < 512; k0 += 32) {
            bf16x8 af = ldfrag(ap + k0 + ko);
            #pragma unroll
            for (int ni = 0; ni < 4; ++ni) {
                bf16x8 bq = ldfrag(ftsT + (long)(wn + ni * 16 + c0) * 8192 + b * 512 + k0 + ko);
                acc[ni] = __builtin_amdgcn_mfma_f32_16x16x32_bf16(af, bq, acc[ni], 0, 0, 0);
            }
        }
        #pragma unroll
        for (int ni = 0; ni < 4; ++ni) {
            const int col = wn + ni * 16 + c0;
            ushort4 o;
            unsigned short* e = (unsigned short*)&o;
            #pragma unroll
            for (int j = 0; j < 4; ++j) {
                unsigned short v = f2b(acc[ni][j]);
                e[j] = v;
                Ot[(r0 + j) * 264 + col] = v;
            }
            *reinterpret_cast<ushort4*>(
                &outT[(long)b * 131072 + (long)col * 512 + m0 + r0]) = o;
        }
    }
    __syncthreads();

    // ---- phase 2: qk[16][512] = Ot[16,256] @ qkT^T  (direct) ----
    {
        const int wn = wave << 7;   // waves 0,1 = q cols; 2,3 = k cols
        f32x4 acc[8] = {};
        #pragma unroll 2
        for (int k0 = 0; k0 < 256; k0 += 32) {
            bf16x8 af = ldfrag(&Ot[c0 * 264 + k0 + ko]);
            #pragma unroll
            for (int ni = 0; ni < 8; ++ni) {
                bf16x8 bq = ldfrag(qkT + (long)(wn + ni * 16 + c0) * 256 + k0 + ko);
                acc[ni] = __builtin_amdgcn_mfma_f32_16x16x32_bf16(af, bq, acc[ni], 0, 0, 0);
            }
        }
        float rs[4] = {};
        #pragma unroll
        for (int ni = 0; ni < 8; ++ni)
            #pragma unroll
            for (int j = 0; j < 4; ++j) { float x = acc[ni][j]; rs[j] += x * x; }
        #pragma unroll
        for (int o = 1; o <= 8; o <<= 1)
            #pragma unroll
            for (int j = 0; j < 4; ++j) rs[j] += __shfl_xor(rs[j], o);
        if (c0 == 0) {
            #pragma unroll
            for (int j = 0; j < 4; ++j) sred[r0 + j][wave] = rs[j];
        }
        __syncthreads();
        float inv[4];
        #pragma unroll
        for (int j = 0; j < 4; ++j) {
            const int rr = r0 + j;
            float sq = sred[rr][0] + sred[rr][1];
            float sk = sred[rr][2] + sred[rr][3];
            inv[j] = 1.f / fmaxf(sqrtf(wave < 2 ? sq : sk), 1e-12f);
        }
        #pragma unroll
        for (int ni = 0; ni < 8; ++ni)
            #pragma unroll
            for (int j = 0; j < 4; ++j) {
                const long rowg = (long)b * 512 + m0 + r0 + j;
                const int col = wn + ni * 16 + c0;
                unsigned short v = f2b(acc[ni][j] * inv[j]);
                if (wave < 2) q_bf[rowg * 256 + col] = v;
                else          k_bf[rowg * 256 + col - 256] = v;
            }
    }
}

// ---------------- merged: attention+MLP (odd) | h2 branch (even) — direct fragments ----------------
__global__ __launch_bounds__(256) void attmlp_h2(
    const unsigned short* __restrict__ q_bf,   // [16][512][256]
    const unsigned short* __restrict__ k_bf,   // [16][512][256]
    const unsigned short* __restrict__ adj_bf, // [16][512][512]
    const float* __restrict__ drop,            // [16][512][512]
    const unsigned short* __restrict__ outT,   // [16][256][512]
    const unsigned short* __restrict__ w1T,    // [256][256]
    const unsigned short* __restrict__ w2T,    // [256][256]
    const float* __restrict__ bias1,
    const float* __restrict__ av, const float* __restrict__ a1,
    unsigned short* __restrict__ n1,           // [8192][256]
    float* __restrict__ psum1,                 // [256][256]
    float* __restrict__ rowpart,               // [8192]
    const unsigned short* __restrict__ diff_bf,// [16][512][512]
    const unsigned short* __restrict__ fts2T,  // [256][8192]
    const float* __restrict__ bias2, const float* __restrict__ a2,
    unsigned short* __restrict__ n2,           // [8192][256]
    float* __restrict__ psum2)                 // [256][256]
{
    __shared__ unsigned char smem[33280];      // Pls [32][520] bf16 | T [32][264] bf16
    __shared__ float redm[32][4], reds[32][4];

    const int idx = blockIdx.x >> 1;
    const int tid = threadIdx.x, lane = tid & 63, wave = tid >> 6;
    const int hi = lane >> 4, c0 = lane & 15, r0 = hi << 2;
    const int ko = hi << 3;   // fragment k-offset (elements)

    if (blockIdx.x & 1) {
        // ================= attention + MLP role =================
        unsigned short* Pls = (unsigned short*)smem;   // [32][520]
        unsigned short* T   = (unsigned short*)smem;   // [32][264] (after PV)

        const int b  = idx >> 4;
        const int m0 = (idx & 15) << 5;
        const unsigned short* qp = q_bf + (long)b * 131072;
        const unsigned short* kp = k_bf + (long)b * 131072;
        const unsigned short* ot = outT + (long)b * 131072;
        const unsigned short* ap = adj_bf + ((long)b * 512 + m0) * 512;
        const float*          dp = drop   + ((long)b * 512 + m0) * 512;

        // ---- phase 1: scores[32][512] = q[32,256] @ k^T ----
        {
            const int wn = wave << 7;
            f32x4 acc[2][8] = {};
            #pragma unroll 2
            for (int k0 = 0; k0 < 256; k0 += 32) {
                bf16x8 af[2];
                #pragma unroll
                for (int mi = 0; mi < 2; ++mi)
                    af[mi] = ldfrag(qp + (long)(m0 + mi * 16 + c0) * 256 + k0 + ko);
                #pragma unroll
                for (int ni = 0; ni < 8; ++ni) {
                    bf16x8 bq = ldfrag(kp + (long)(wn + ni * 16 + c0) * 256 + k0 + ko);
                    #pragma unroll
                    for (int mi = 0; mi < 2; ++mi)
                        acc[mi][ni] = __builtin_amdgcn_mfma_f32_16x16x32_bf16(
                            af[mi], bq, acc[mi][ni], 0, 0, 0);
                }
            }

            float rmax[2][4];
            #pragma unroll
            for (int mi = 0; mi < 2; ++mi)
                #pragma unroll
                for (int j = 0; j < 4; ++j) rmax[mi][j] = -3.0e38f;
            #pragma unroll
            for (int mi = 0; mi < 2; ++mi)
                #pragma unroll
                for (int ni = 0; ni < 8; ++ni)
                    #pragma unroll
                    for (int j = 0; j < 4; ++j) {
                        const int rowl = mi * 16 + r0 + j;
                        const int col  = wn + ni * 16 + c0;
                        float s = acc[mi][ni][j];
                        if (col == m0 + rowl)
                            rowpart[(long)b * 512 + m0 + rowl] = 2.f - 2.f * s;
                        bool m = ap[(long)rowl * 512 + col] != 0;
                        s = m ? s : -3.0e38f;
                        acc[mi][ni][j] = s;
                        rmax[mi][j] = fmaxf(rmax[mi][j], s);
                    }
            #pragma unroll
            for (int o = 1; o <= 8; o <<= 1)
                #pragma unroll
                for (int mi = 0; mi < 2; ++mi)
                    #pragma unroll
                    for (int j = 0; j < 4; ++j)
                        rmax[mi][j] = fmaxf(rmax[mi][j], __shfl_xor(rmax[mi][j], o));
            if (c0 == 0) {
                #pragma unroll
                for (int mi = 0; mi < 2; ++mi)
                    #pragma unroll
                    for (int j = 0; j < 4; ++j) redm[mi * 16 + r0 + j][wave] = rmax[mi][j];
            }
            __syncthreads();
            float mx[2][4], rsum[2][4];
            #pragma unroll
            for (int mi = 0; mi < 2; ++mi)
                #pragma unroll
                for (int j = 0; j < 4; ++j) {
                    const int rr = mi * 16 + r0 + j;
                    mx[mi][j] = fmaxf(fmaxf(redm[rr][0], redm[rr][1]),
                                      fmaxf(redm[rr][2], redm[rr][3]));
                    rsum[mi][j] = 0.f;
                }
            #pragma unroll
            for (int mi = 0; mi < 2; ++mi)
                #pragma unroll
                for (int ni = 0; ni < 8; ++ni)
                    #pragma unroll
                    for (int j = 0; j < 4; ++j) {
                        float e = __expf(acc[mi][ni][j] - mx[mi][j]);
                        acc[mi][ni][j] = e;
                        rsum[mi][j] += e;
                    }
            #pragma unroll
            for (int o = 1; o <= 8; o <<= 1)
                #pragma unroll
                for (int mi = 0; mi < 2; ++mi)
                    #pragma unroll
                    for (int j = 0; j < 4; ++j) rsum[mi][j] += __shfl_xor(rsum[mi][j], o);
            if (c0 == 0) {
                #pragma unroll
                for (int mi = 0; mi < 2; ++mi)
                    #pragma unroll
                    for (int j = 0; j < 4; ++j) reds[mi * 16 + r0 + j][wave] = rsum[mi][j];
            }
            __syncthreads();
            float inv[2][4];
            #pragma unroll
            for (int mi = 0; mi < 2; ++mi)
                #pragma unroll
                for (int j = 0; j < 4; ++j) {
                    const int rr = mi * 16 + r0 + j;
                    inv[mi][j] = 1.f / (reds[rr][0] + reds[rr][1] + reds[rr][2] + reds[rr][3]);
                }
            #pragma unroll
            for (int mi = 0; mi < 2; ++mi)
                #pragma unroll
                for (int ni = 0; ni < 8; ++ni)
                    #pragma unroll
                    for (int j = 0; j < 4; ++j) {
                        const int rowl = mi * 16 + r0 + j;
                        const int col  = wn + ni * 16 + c0;
                        float p = acc[mi][ni][j] * inv[mi][j] * dp[(long)rowl * 512 + col];
                        Pls[rowl * 520 + col] = f2b(p);
                    }
        }
        __syncthreads();

        // ---- phase 2: agg[32][256] = P[32,512] @ out[512,256] ----
        f32x4 acc2[2][4] = {};
        {
            const int wn = wave << 6;
            #pragma unroll 2
            for (int k0 = 0; k0 < 512; k0 += 32) {
                bf16x8 af[2];
                #pragma unroll
                for (int mi = 0; mi < 2; ++mi)
                    af[mi] = ldfrag(&Pls[(mi * 16 + c0) * 520 + k0 + ko]);
                #pragma unroll
                for (int ni = 0; ni < 4; ++ni) {
                    bf16x8 bq = ldfrag(ot + (long)(wn + ni * 16 + c0) * 512 + k0 + ko);
                    #pragma unroll
                    for (int mi = 0; mi < 2; ++mi)
                        acc2[mi][ni] = __builtin_amdgcn_mfma_f32_16x16x32_bf16(
                            af[mi], bq, acc2[mi][ni], 0, 0, 0);
                }
            }
        }
        __syncthreads();

        // ---- MLP stage 1: t1 = prelu(agg @ w1) ----
        const int wn6 = wave << 6;
        const float alphav = av[0];
        #pragma unroll
        for (int mi = 0; mi < 2; ++mi)
            #pragma unroll
            for (int ni = 0; ni < 4; ++ni)
                #pragma unroll
                for (int j = 0; j < 4; ++j)
                    T[(mi * 16 + r0 + j) * 264 + wn6 + ni * 16 + c0] = f2b(acc2[mi][ni][j]);
        __syncthreads();
        f32x4 acct[2][4] = {};
        #pragma unroll 2
        for (int k0 = 0; k0 < 256; k0 += 32) {
            bf16x8 af[2];
            #pragma unroll
            for (int mi = 0; mi < 2; ++mi)
                af[mi] = ldfrag(&T[(mi * 16 + c0) * 264 + k0 + ko]);
            #pragma unroll
            for (int ni = 0; ni < 4; ++ni) {
                bf16x8 bq = ldfrag(w1T + (long)(wn6 + ni * 16 + c0) * 256 + k0 + ko);
                #pragma unroll
                for (int mi = 0; mi < 2; ++mi)
                    acct[mi][ni] = __builtin_amdgcn_mfma_f32_16x16x32_bf16(
                        af[mi], bq, acct[mi][ni], 0, 0, 0);
            }
        }
        __syncthreads();
        #pragma unroll
        for (int mi = 0; mi < 2; ++mi)
            #pragma unroll
            for (int ni = 0; ni < 4; ++ni)
                #pragma unroll
                for (int j = 0; j < 4; ++j) {
                    float x = acct[mi][ni][j];
                    x = (x >= 0.f) ? x : alphav * x;
                    T[(mi * 16 + r0 + j) * 264 + wn6 + ni * 16 + c0] = f2b(x);
                }
        __syncthreads();

        // ---- MLP stage 2: h1 = prelu(t1 @ w2 + bias) ----
        f32x4 acc3[2][4] = {};
        #pragma unroll 2
        for (int k0 = 0; k0 < 256; k0 += 32) {
            bf16x8 af[2];
            #pragma unroll
            for (int mi = 0; mi < 2; ++mi)
                af[mi] = ldfrag(&T[(mi * 16 + c0) * 264 + k0 + ko]);
            #pragma unroll
            for (int ni = 0; ni < 4; ++ni) {
                bf16x8 bq = ldfrag(w2T + (long)(wn6 + ni * 16 + c0) * 256 + k0 + ko);
                #pragma unroll
                for (int mi = 0; mi < 2; ++mi)
                    acc3[mi][ni] = __builtin_amdgcn_mfma_f32_16x16x32_bf16(
                        af[mi], bq, acc3[mi][ni], 0, 0, 0);
            }
        }

        // ---- epilogue: bias + prelu + row l2norm + psum + n1 ----
        const float alpha1 = a1[0];
        float rs[2][4] = {};
        #pragma unroll
        for (int ni = 0; ni < 4; ++ni) {
            const float bv = bias1[wn6 + ni * 16 + c0];
            #pragma unroll
            for (int mi = 0; mi < 2; ++mi)
                #pragma unroll
                for (int j = 0; j < 4; ++j) {
                    float x = acc3[mi][ni][j] + bv;
                    x = (x >= 0.f) ? x : alpha1 * x;
                    acc3[mi][ni][j] = x;
                    rs[mi][j] += x * x;
                }
        }
        #pragma unroll
        for (int o = 1; o <= 8; o <<= 1)
            #pragma unroll
            for (int mi = 0; mi < 2; ++mi)
                #pragma unroll
                for (int j = 0; j < 4; ++j) rs[mi][j] += __shfl_xor(rs[mi][j], o);
        __syncthreads();
        if (c0 == 0) {
            #pragma unroll
            for (int mi = 0; mi < 2; ++mi)
                #pragma unroll
                for (int j = 0; j < 4; ++j) redm[mi * 16 + r0 + j][wave] = rs[mi][j];
        }
        __syncthreads();
        float inv2[2][4];
        #pragma unroll
        for (int mi = 0; mi < 2; ++mi)
            #pragma unroll
            for (int j = 0; j < 4; ++j) {
                const int rr = mi * 16 + r0 + j;
                float s = redm[rr][0] + redm[rr][1] + redm[rr][2] + redm[rr][3];
                inv2[mi][j] = 1.f / fmaxf(sqrtf(s), 1e-12f);
            }
        float cs[4];
        #pragma unroll
        for (int ni = 0; ni < 4; ++ni) {
            float s = 0.f;
            #pragma unroll
            for (int mi = 0; mi < 2; ++mi)
                #pragma unroll
                for (int j = 0; j < 4; ++j) s += acc3[mi][ni][j];
            s += __shfl_xor(s, 16);
            s += __shfl_xor(s, 32);
            cs[ni] = s;
        }
        if (lane < 16) {
            #pragma unroll
            for (int ni = 0; ni < 4; ++ni)
                psum1[(long)idx * 256 + wn6 + ni * 16 + lane] = cs[ni];
        }
        const long row0g = (long)b * 512 + m0;
        #pragma unroll
        for (int mi = 0; mi < 2; ++mi)
            #pragma unroll
            for (int ni = 0; ni < 4; ++ni)
                #pragma unroll
                for (int j = 0; j < 4; ++j)
                    n1[(row0g + mi * 16 + r0 + j) * 256 + wn6 + ni * 16 + c0] =
                        f2b(acc3[mi][ni][j] * inv2[mi][j]);
    } else {
        // ================= h2 branch role (diff GEMM + norm, all direct) =================
        const int z = idx >> 4;           // batch
        const int arow0 = (idx & 15) << 5;
        const unsigned short* ad = diff_bf + (long)z * 262144;
        const unsigned short* bt = fts2T + z * 512;
        const int wn = wave << 6;

        f32x4 acc[2][4] = {};
        #pragma unroll 2
        for (int k0 = 0; k0 < 512; k0 += 32) {
            bf16x8 af[2];
            #pragma unroll
            for (int mi = 0; mi < 2; ++mi)
                af[mi] = ldfrag(ad + (long)(arow0 + mi * 16 + c0) * 512 + k0 + ko);
            #pragma unroll
            for (int ni = 0; ni < 4; ++ni) {
                bf16x8 bq = ldfrag(bt + (long)(wn + ni * 16 + c0) * 8192 + k0 + ko);
                #pragma unroll
                for (int mi = 0; mi < 2; ++mi)
                    acc[mi][ni] = __builtin_amdgcn_mfma_f32_16x16x32_bf16(
                        af[mi], bq, acc[mi][ni], 0, 0, 0);
            }
        }

        const float alpha = a2[0];
        float rs[2][4] = {};
        #pragma unroll
        for (int ni = 0; ni < 4; ++ni) {
            const float bv = bias2[wn + ni * 16 + c0];
            #pragma unroll
            for (int mi = 0; mi < 2; ++mi)
                #pragma unroll
                for (int j = 0; j < 4; ++j) {
                    float x = acc[mi][ni][j] + bv;
                    x = (x >= 0.f) ? x : alpha * x;
                    acc[mi][ni][j] = x;
                    rs[mi][j] += x * x;
                }
        }
        #pragma unroll
        for (int o = 1; o <= 8; o <<= 1)
            #pragma unroll
            for (int mi = 0; mi < 2; ++mi)
                #pragma unroll
                for (int j = 0; j < 4; ++j) rs[mi][j] += __shfl_xor(rs[mi][j], o);
        if (c0 == 0) {
            #pragma unroll
            for (int mi = 0; mi < 2; ++mi)
                #pragma unroll
                for (int j = 0; j < 4; ++j) redm[mi * 16 + r0 + j][wave] = rs[mi][j];
        }
        __syncthreads();
        float inv[2][4];
        #pragma unroll
        for (int mi = 0; mi < 2; ++mi)
            #pragma unroll
            for (int j = 0; j < 4; ++j) {
                const int rr = mi * 16 + r0 + j;
                float s = redm[rr][0] + redm[rr][1] + redm[rr][2] + redm[rr][3];
                inv[mi][j] = 1.f / fmaxf(sqrtf(s), 1e-12f);
            }
        float cs[4];
        #pragma unroll
        for (int ni = 0; ni < 4; ++ni) {
            float s = 0.f;
            #pragma unroll
            for (int mi = 0; mi < 2; ++mi)
                #pragma unroll
                for (int j = 0; j < 4; ++j) s += acc[mi][ni][j];
            s += __shfl_xor(s, 16);
            s += __shfl_xor(s, 32);
            cs[ni] = s;
        }
        if (lane < 16) {
            #pragma unroll
            for (int ni = 0; ni < 4; ++ni)
                psum2[(long)idx * 256 + wn + ni * 16 + lane] = cs[ni];
        }
        const long grow0 = (long)idx * 32;
        #pragma unroll
        for (int mi = 0; mi < 2; ++mi)
            #pragma unroll
            for (int ni = 0; ni < 4; ++ni)
                #pragma unroll
                for (int j = 0; j < 4; ++j)
                    n2[(grow0 + mi * 16 + r0 + j) * 256 + wn + ni * 16 + c0] =
                        f2b(acc[mi][ni][j] * inv[mi][j]);
    }
}

// ---------------------------------------------------------------------------
// Workspace layout (bytes). End = 49,872,896 (~47.6 MB).
// ---------------------------------------------------------------------------
static constexpr long OFF_SEQ_BF  = 0;                  // [8192,128] bf16, 2MB
static constexpr long OFF_FC1T    = 2097152;            // [2][256][128]
static constexpr long OFF_QWT     = 2228224;            // [512][256] stacked q|k
static constexpr long OFF_VW1T    = 2490368;
static constexpr long OFF_VW2T    = 2621440;
static constexpr long OFF_ADJ     = 3145728;            // 8MB
static constexpr long OFF_DIFF    = 11534336;           // 8MB
static constexpr long OFF_FTST    = 19922944;           // [2][256][8192] 8MB
static constexpr long OFF_OUTT    = 28311552;           // [16][256][512] 4MB
static constexpr long OFF_QBF     = 32505856;           // 4MB
static constexpr long OFF_KBF     = 36700160;           // 4MB
static constexpr long OFF_N1      = 40894464;           // 4MB
static constexpr long OFF_N2      = 45088768;           // 4MB
static constexpr long OFF_PSUM    = 49283072;           // 2x 256KB
static constexpr long OFF_ROWPART = 49807360;           // 32KB

extern "C" void kernel_launch(void* const* d_in, const int* in_sizes, int n_in,
                              void* d_out, int out_size, void* d_ws, size_t ws_size,
                              hipStream_t stream) {
    const float* seq      = (const float*)d_in[0];
    const float* adj      = (const float*)d_in[1];
    const float* diff     = (const float*)d_in[2];
    const float* drop     = (const float*)d_in[3];
    const float* fc1_w    = (const float*)d_in[4];
    const float* q_w      = (const float*)d_in[5];
    const float* k_w      = (const float*)d_in[6];
    const float* v_w1     = (const float*)d_in[7];
    const float* v_w2     = (const float*)d_in[8];
    const float* fc2_w    = (const float*)d_in[9];
    const float* bias1    = (const float*)d_in[10];
    const float* bias2    = (const float*)d_in[11];
    const float* prelu1_a = (const float*)d_in[12];
    const float* prelu2_a = (const float*)d_in[13];
    const float* v_prelu  = (const float*)d_in[14];
    float* out = (float*)d_out;

    char* ws = (char*)d_ws;
    unsigned short* seq_bf  = (unsigned short*)(ws + OFF_SEQ_BF);
    unsigned short* fc1T    = (unsigned short*)(ws + OFF_FC1T);
    unsigned short* fc2T    = (unsigned short*)(ws + OFF_FC1T + 65536);
    unsigned short* qwT     = (unsigned short*)(ws + OFF_QWT);
    unsigned short* kwT     = (unsigned short*)(ws + OFF_QWT + 131072);
    unsigned short* vw1T    = (unsigned short*)(ws + OFF_VW1T);
    unsigned short* vw2T    = (unsigned short*)(ws + OFF_VW2T);
    unsigned short* adj_bf  = (unsigned short*)(ws + OFF_ADJ);
    unsigned short* diff_bf = (unsigned short*)(ws + OFF_DIFF);
    unsigned short* ftsT    = (unsigned short*)(ws + OFF_FTST);
    unsigned short* fts2T   = (unsigned short*)(ws + OFF_FTST + 4194304);
    unsigned short* outT    = (unsigned short*)(ws + OFF_OUTT);
    unsigned short* q_bf    = (unsigned short*)(ws + OFF_QBF);
    unsigned short* k_bf    = (unsigned short*)(ws + OFF_KBF);
    unsigned short* n1_bf   = (unsigned short*)(ws + OFF_N1);
    unsigned short* n2_bf   = (unsigned short*)(ws + OFF_N2);
    float*          psum1   = (float*)(ws + OFF_PSUM);
    float*          psum2   = (float*)(ws + OFF_PSUM + 262144);
    float*          rowpart = (float*)(ws + OFF_ROWPART);

    // 1: conversions + weight transposes
    prep<<<9600, 256, 0, stream>>>(seq, adj, diff, fc1_w, fc2_w, q_w, k_w, v_w1, v_w2,
                                   seq_bf, adj_bf, diff_bf, fc1T, fc2T, qwT, kwT, vw1T, vw2T);

    // 2: ftsT|fts2T = [fc1|fc2]^T @ seq^T  (batched z=2, LDS-staged 64x128)
    gemm_small<<<dim3(64, 4, 2), 256, 0, stream>>>(
        fc1T, seq_bf, ftsT, 128, 128, 128, 8192, 32768, 0, 2097152);

    // 3: out = adj@fts -> outT (+LDS Ot), then qk proj + l2norm  (direct frags)
    gcn1qk<<<dim3(32, 16), 256, 0, stream>>>(adj_bf, ftsT, qwT, outT, q_bf, k_bf);

    // 4: merged attention+MLP | h2 branch  (direct frags)
    attmlp_h2<<<512, 256, 0, stream>>>(
        q_bf, k_bf, adj_bf, drop, outT, vw1T, vw2T, bias1, v_prelu, prelu1_a,
        n1_bf, psum1, rowpart,
        diff_bf, fts2T, bias2, prelu2_a, n2_bf, psum2);

    // 5: node_logits = n1 @ n2^T, 256^2 tile + fused readout (block 0)
    gemm_big<<<1024, 512, 0, stream>>>(
        n1_bf, n2_bf, out,
        psum1, psum2, rowpart, out + 67108864, out + 67109120);

    (void)in_sizes; (void)n_in; (void)out_size; (void)ws_size;
}

// Round 12
// 195.389 us; speedup vs baseline: 1.0258x; 1.0258x over previous
//
#include <hip/hip_runtime.h>
#include <hip/hip_bf16.h>

// ---------------------------------------------------------------------------
// B=16, N=512, DIN=128, DH=256
// out = [node_logits 8192x8192 f32 | graph_logits 16x16 | div_loss]
// R12 = R10 (best measured: 195.5us). Middle-chain GEMMs read MFMA fragments
// directly from global/L2 (no LDS staging); G10 is the 128x128 m97-staged
// GEMM with LDS-bounce nontemporal-store epilogue + fused readout in blk(0,0).
// R11's 256^2 G10 tile regressed (occupancy/TLP loss) and is reverted.
// ---------------------------------------------------------------------------

using bf16x8 = __attribute__((ext_vector_type(8))) short;
using f32x4  = __attribute__((ext_vector_type(4))) float;

__device__ __forceinline__ unsigned short f2b(float f) {
    union { float f; unsigned int u; } x; x.f = f;
    unsigned int r = x.u + 0x7FFFu + ((x.u >> 16) & 1u);   // RNE
    return (unsigned short)(r >> 16);
}
__device__ __forceinline__ void gload_lds16(const void* g, void* l) {
    __builtin_amdgcn_global_load_lds(
        (const __attribute__((address_space(1))) void*)g,
        (__attribute__((address_space(3))) void*)l, 16, 0, 0);
}
__device__ __forceinline__ bf16x8 ldfrag(const unsigned short* p) {
    return *reinterpret_cast<const bf16x8*>(p);
}

// ---------------- prep: conv3 + all 6 weight transposes ----------------
__global__ __launch_bounds__(256) void prep(
    const float* __restrict__ seq, const float* __restrict__ adj,
    const float* __restrict__ diff,
    const float* __restrict__ fc1, const float* __restrict__ fc2,
    const float* __restrict__ qw,  const float* __restrict__ kw,
    const float* __restrict__ v1,  const float* __restrict__ v2,
    unsigned short* __restrict__ seq_bf, unsigned short* __restrict__ adj_bf,
    unsigned short* __restrict__ diff_bf,
    unsigned short* fc1T, unsigned short* fc2T, unsigned short* qwT,
    unsigned short* kwT,  unsigned short* v1T,  unsigned short* v2T)
{
    __shared__ float t[32][33];
    const int bid = blockIdx.x, tid = threadIdx.x;
    if (bid < 9216) {
        long i = (long)bid * 256 + tid;   // quad index
        const float* src; unsigned short* dst; long off;
        if (i < 262144)       { src = seq;  dst = seq_bf;  off = i; }
        else if (i < 1310720) { src = adj;  dst = adj_bf;  off = i - 262144; }
        else                  { src = diff; dst = diff_bf; off = i - 1310720; }
        float4 v = reinterpret_cast<const float4*>(src)[off];
        ushort4 o; o.x = f2b(v.x); o.y = f2b(v.y); o.z = f2b(v.z); o.w = f2b(v.w);
        reinterpret_cast<ushort4*>(dst)[off] = o;
        return;
    }
    const int r = bid - 9216;
    const int z = r >> 6;
    const float* in; unsigned short* op; int R;
    if      (z == 0) { in = fc1; op = fc1T; R = 128; }
    else if (z == 1) { in = fc2; op = fc2T; R = 128; }
    else if (z == 2) { in = qw;  op = qwT;  R = 256; }
    else if (z == 3) { in = kw;  op = kwT;  R = 256; }
    else if (z == 4) { in = v1;  op = v1T;  R = 256; }
    else             { in = v2;  op = v2T;  R = 256; }
    const int c0 = (r & 7) * 32, r0 = ((r >> 3) & 7) * 32;
    if (r0 >= R) return;
    const int x = tid & 31, y = tid >> 5;
    for (int i = 0; i < 32; i += 8) t[y + i][x] = in[(long)(r0 + y + i) * 256 + c0 + x];
    __syncthreads();
    for (int i = 0; i < 32; i += 8)
        op[(long)(c0 + y + i) * R + r0 + x] = f2b(t[x][y + i]);
}

// ---------------- MFMA NT GEMM (m97 staging), TBM x 128 tile, BK=64 ----------------
// WF: LDS-bounce epilogue -> coalesced nontemporal f32x4 stores.
// RD: block(0,0) additionally performs the readout (means/norms/graph16/divloss).
#define BN 128
#define BK 64

template<int TBM, bool WF, bool WB, bool SWZ, bool RD>
__global__ __launch_bounds__(256) void gemm_nt(
    const unsigned short* __restrict__ A, const unsigned short* __restrict__ Bt,
    float* __restrict__ Cf, unsigned short* __restrict__ Cb,
    int M, int Nn, int K, int lda, int ldb, int ldc,
    long sA, long sB, long sC,
    const float* __restrict__ rd_psum1, const float* __restrict__ rd_psum2,
    const float* __restrict__ rd_rowpart,
    float* __restrict__ rd_outg, float* __restrict__ rd_outdiv)
{
    constexpr int MI = TBM / 32;
    __shared__ unsigned char smem_g[(TBM + BN) * BK * 2];
    __shared__ float rd_invn[32];
    __shared__ float rd_red[4];
    unsigned short* As = (unsigned short*)smem_g;                    // [TBM][BK]
    unsigned short* Bs = (unsigned short*)(smem_g + TBM * BK * 2);   // [BN][BK]
    const int b = blockIdx.z;
    A  += (long)b * sA;
    Bt += (long)b * sB;
    const long cbase = (long)b * sC;

    int tx, ty;
    if (SWZ) {
        int bid = blockIdx.y * gridDim.x + blockIdx.x;
        int nwg = gridDim.x * gridDim.y;
        int cpx = nwg >> 3;
        int s = (bid & 7) * cpx + (bid >> 3);
        tx = s % gridDim.x; ty = s / gridDim.x;
    } else { tx = blockIdx.x; ty = blockIdx.y; }
    const int tile_m = ty * TBM;
    const int tile_n = tx * BN;

    const int tid  = threadIdx.x;
    const int lane = tid & 63;
    const int wave = tid >> 6;
    const int wm = (wave >> 1) * (TBM / 2);
    const int wn = (wave & 1) << 6;
    const int lrow = lane >> 3;
    const int lcol = (lane & 7) << 3;

    f32x4 acc[MI][4] = {};

    for (int k0 = 0; k0 < K; k0 += BK) {
        #pragma unroll
        for (int i = 0; i < TBM / 32; ++i) {
            const int rb = (i * 4 + wave) * 8;
            gload_lds16(A + (long)(tile_m + rb + lrow) * lda + k0 + lcol, &As[rb * BK]);
        }
        #pragma unroll
        for (int i = 0; i < 4; ++i) {
            const int rb = (i * 4 + wave) * 8;
            gload_lds16(Bt + (long)(tile_n + rb + lrow) * ldb + k0 + lcol, &Bs[rb * BK]);
        }
        __syncthreads();
        #pragma unroll
        for (int ks = 0; ks < 2; ++ks) {
            const int kk = ks * 32 + ((lane >> 4) << 3);
            bf16x8 af[MI], bq[4];
            #pragma unroll
            for (int mi = 0; mi < MI; ++mi)
                af[mi] = ldfrag(&As[(wm + (lane & 15) + mi * 16) * BK + kk]);
            #pragma unroll
            for (int ni = 0; ni < 4; ++ni)
                bq[ni] = ldfrag(&Bs[(wn + (lane & 15) + ni * 16) * BK + kk]);
            #pragma unroll
            for (int mi = 0; mi < MI; ++mi)
                #pragma unroll
                for (int ni = 0; ni < 4; ++ni)
                    acc[mi][ni] = __builtin_amdgcn_mfma_f32_16x16x32_bf16(
                        af[mi], bq[ni], acc[mi][ni], 0, 0, 0);
        }
        __syncthreads();
    }

    const int c0 = lane & 15;
    const int r0 = (lane >> 4) << 2;

    if (WB) {
        #pragma unroll
        for (int ni = 0; ni < 4; ++ni) {
            const int col = tile_n + wn + ni * 16 + c0;
            #pragma unroll
            for (int mi = 0; mi < MI; ++mi) {
                const int row0 = tile_m + wm + mi * 16 + r0;
                #pragma unroll
                for (int j = 0; j < 4; ++j)
                    Cb[cbase + (long)(row0 + j) * ldc + col] = f2b(acc[mi][ni][j]);
            }
        }
    }
    if (WF) {
        float* bounce = (float*)smem_g;           // [64][128] f32
        const int tr = tid >> 5;                   // 0..7
        const int tc = (tid & 31) << 2;            // 0,4,...,124
        #pragma unroll
        for (int h = 0; h < 2; ++h) {
            __syncthreads();
            if ((wave >> 1) == h) {
                #pragma unroll
                for (int mi = 0; mi < MI; ++mi)
                    #pragma unroll
                    for (int ni = 0; ni < 4; ++ni)
                        #pragma unroll
                        for (int j = 0; j < 4; ++j)
                            bounce[(mi * 16 + r0 + j) * 128 + wn + ni * 16 + c0] =
                                acc[mi][ni][j];
            }
            __syncthreads();
            #pragma unroll
            for (int p = 0; p < 8; ++p) {
                const int rl = p * 8 + tr;
                f32x4 v = *reinterpret_cast<const f32x4*>(&bounce[rl * 128 + tc]);
                __builtin_nontemporal_store(v, reinterpret_cast<f32x4*>(
                    &Cf[cbase + (long)(tile_m + h * 64 + rl) * ldc + tile_n + tc]));
            }
        }
    }
    if (RD) {
        if (blockIdx.x == 0 && blockIdx.y == 0) {
            __syncthreads();
            float* c1s = (float*)smem_g;          // [16][256]
            float* c2s = c1s + 4096;              // [16][256]
            const int t = tid;
            for (int g = 0; g < 16; ++g) {
                float s1 = 0.f, s2 = 0.f;
                #pragma unroll
                for (int c = 0; c < 16; ++c) {
                    s1 += rd_psum1[(long)(g * 16 + c) * 256 + t];
                    s2 += rd_psum2[(long)(g * 16 + c) * 256 + t];
                }
                c1s[g * 256 + t] = s1 * (1.f / 512.f);
                c2s[g * 256 + t] = s2 * (1.f / 512.f);
            }
            __syncthreads();
            if (t < 32) {
                const float* row = (t < 16) ? &c1s[t * 256] : &c2s[(t - 16) * 256];
                float ss = 0.f;
                for (int h = 0; h < 256; ++h) { float v = row[h]; ss += v * v; }
                rd_invn[t] = 1.f / fmaxf(sqrtf(ss), 1e-12f);
            }
            __syncthreads();
            const int ii = t >> 4, jj = t & 15;
            float s = 0.f;
            for (int h = 0; h < 256; ++h) s += c1s[ii * 256 + h] * c2s[jj * 256 + h];
            rd_outg[ii * 16 + jj] = s * rd_invn[ii] * rd_invn[16 + jj];
            float ds = 0.f;
            for (int i = t; i < 8192; i += 256) ds += rd_rowpart[i];
            #pragma unroll
            for (int o = 32; o; o >>= 1) ds += __shfl_xor(ds, o);
            if ((t & 63) == 0) rd_red[t >> 6] = ds;
            __syncthreads();
            if (t == 0)
                rd_outdiv[0] = (rd_red[0] + rd_red[1] + rd_red[2] + rd_red[3]) * (1.f / 8192.f);
        }
    }
}

// ---------------- gcn1qk: out=adj@fts (->outT+LDS Ot) then qk-proj + l2norm ----------------
// Direct-fragment version: B (and adj A) fragments straight from global/L2.
// 16 rows/block, grid (32,16) = 512 blocks. LDS: Ot 8.4KB only.
__global__ __launch_bounds__(256) void gcn1qk(
    const unsigned short* __restrict__ adj_bf, // [16][512][512]
    const unsigned short* __restrict__ ftsT,   // [256][8192]
    const unsigned short* __restrict__ qkT,    // [512][256] stacked q|k
    unsigned short* __restrict__ outT,         // [16][256][512]
    unsigned short* __restrict__ q_bf,         // [16][512][256]
    unsigned short* __restrict__ k_bf)         // [16][512][256]
{
    __shared__ unsigned short Ot[16 * 264];
    __shared__ float sred[16][4];

    const int b  = blockIdx.y;
    const int m0 = blockIdx.x << 4;
    const int tid = threadIdx.x, lane = tid & 63, wave = tid >> 6;
    const int hi = lane >> 4, c0 = lane & 15, r0 = hi << 2;
    const int ko = hi << 3;   // fragment k-offset (elements)

    // ---- phase 1: out[16][256] = adj[16,512] @ fts[512,256]  (B = ftsT rows) ----
    {
        const int wn = wave << 6;
        const unsigned short* ap = adj_bf + ((long)b * 512 + m0 + c0) * 512;
        f32x4 acc[4] = {};
        #pragma unroll 2
        for (int k0 = 0; k0 < 512; k0 += 32) {
            bf16x8 af = ldfrag(ap + k0 + ko);
            #pragma unroll
            for (int ni = 0; ni < 4; ++ni) {
                bf16x8 bq = ldfrag(ftsT + (long)(wn + ni * 16 + c0) * 8192 + b * 512 + k0 + ko);
                acc[ni] = __builtin_amdgcn_mfma_f32_16x16x32_bf16(af, bq, acc[ni], 0, 0, 0);
            }
        }
        // epilogue: Ot (LDS) + outT (global, transposed)
        #pragma unroll
        for (int ni = 0; ni < 4; ++ni) {
            const int col = wn + ni * 16 + c0;
            ushort4 o;
            unsigned short* e = (unsigned short*)&o;
            #pragma unroll
            for (int j = 0; j < 4; ++j) {
                unsigned short v = f2b(acc[ni][j]);
                e[j] = v;
                Ot[(r0 + j) * 264 + col] = v;
            }
            *reinterpret_cast<ushort4*>(
                &outT[(long)b * 131072 + (long)col * 512 + m0 + r0]) = o;
        }
    }
    __syncthreads();

    // ---- phase 2: qk[16][512] = Ot[16,256] @ qkT^T  (B = qkT rows, direct) ----
    {
        const int wn = wave << 7;   // waves 0,1 = q cols; 2,3 = k cols
        f32x4 acc[8] = {};
        #pragma unroll 2
        for (int k0 = 0; k0 < 256; k0 += 32) {
            bf16x8 af = ldfrag(&Ot[c0 * 264 + k0 + ko]);
            #pragma unroll
            for (int ni = 0; ni < 8; ++ni) {
                bf16x8 bq = ldfrag(qkT + (long)(wn + ni * 16 + c0) * 256 + k0 + ko);
                acc[ni] = __builtin_amdgcn_mfma_f32_16x16x32_bf16(af, bq, acc[ni], 0, 0, 0);
            }
        }
        // per-row sumsq (each wave's 128 cols entirely q or entirely k)
        float rs[4] = {};
        #pragma unroll
        for (int ni = 0; ni < 8; ++ni)
            #pragma unroll
            for (int j = 0; j < 4; ++j) { float x = acc[ni][j]; rs[j] += x * x; }
        #pragma unroll
        for (int o = 1; o <= 8; o <<= 1)
            #pragma unroll
            for (int j = 0; j < 4; ++j) rs[j] += __shfl_xor(rs[j], o);
        if (c0 == 0) {
            #pragma unroll
            for (int j = 0; j < 4; ++j) sred[r0 + j][wave] = rs[j];
        }
        __syncthreads();
        float inv[4];
        #pragma unroll
        for (int j = 0; j < 4; ++j) {
            const int rr = r0 + j;
            float sq = sred[rr][0] + sred[rr][1];
            float sk = sred[rr][2] + sred[rr][3];
            inv[j] = 1.f / fmaxf(sqrtf(wave < 2 ? sq : sk), 1e-12f);
        }
        #pragma unroll
        for (int ni = 0; ni < 8; ++ni)
            #pragma unroll
            for (int j = 0; j < 4; ++j) {
                const long rowg = (long)b * 512 + m0 + r0 + j;
                const int col = wn + ni * 16 + c0;
                unsigned short v = f2b(acc[ni][j] * inv[j]);
                if (wave < 2) q_bf[rowg * 256 + col] = v;
                else          k_bf[rowg * 256 + col - 256] = v;
            }
    }
}

// ---------------- merged: attention+MLP (odd) | h2 branch (even) — direct fragments ----------------
__global__ __launch_bounds__(256) void attmlp_h2(
    const unsigned short* __restrict__ q_bf,   // [16][512][256]
    const unsigned short* __restrict__ k_bf,   // [16][512][256]
    const unsigned short* __restrict__ adj_bf, // [16][512][512]
    const float* __restrict__ drop,            // [16][512][512]
    const unsigned short* __restrict__ outT,   // [16][256][512]
    const unsigned short* __restrict__ w1T,    // [256][256]
    const unsigned short* __restrict__ w2T,    // [256][256]
    const float* __restrict__ bias1,
    const float* __restrict__ av, const float* __restrict__ a1,
    unsigned short* __restrict__ n1,           // [8192][256]
    float* __restrict__ psum1,                 // [256][256]
    float* __restrict__ rowpart,               // [8192]
    const unsigned short* __restrict__ diff_bf,// [16][512][512]
    const unsigned short* __restrict__ fts2T,  // [256][8192]
    const float* __restrict__ bias2, const float* __restrict__ a2,
    unsigned short* __restrict__ n2,           // [8192][256]
    float* __restrict__ psum2)                 // [256][256]
{
    __shared__ unsigned char smem[33280];      // Pls [32][520] bf16 | T [32][264] bf16
    __shared__ float redm[32][4], reds[32][4];

    const int idx = blockIdx.x >> 1;
    const int tid = threadIdx.x, lane = tid & 63, wave = tid >> 6;
    const int hi = lane >> 4, c0 = lane & 15, r0 = hi << 2;
    const int ko = hi << 3;   // fragment k-offset (elements)

    if (blockIdx.x & 1) {
        // ================= attention + MLP role =================
        unsigned short* Pls = (unsigned short*)smem;   // [32][520]
        unsigned short* T   = (unsigned short*)smem;   // [32][264] (after PV)

        const int b  = idx >> 4;
        const int m0 = (idx & 15) << 5;
        const unsigned short* qp = q_bf + (long)b * 131072;
        const unsigned short* kp = k_bf + (long)b * 131072;
        const unsigned short* ot = outT + (long)b * 131072;
        const unsigned short* ap = adj_bf + ((long)b * 512 + m0) * 512;
        const float*          dp = drop   + ((long)b * 512 + m0) * 512;

        // ---- phase 1: scores[32][512] = q[32,256] @ k^T  (all direct) ----
        {
            const int wn = wave << 7;
            f32x4 acc[2][8] = {};
            #pragma unroll 2
            for (int k0 = 0; k0 < 256; k0 += 32) {
                bf16x8 af[2];
                #pragma unroll
                for (int mi = 0; mi < 2; ++mi)
                    af[mi] = ldfrag(qp + (long)(m0 + mi * 16 + c0) * 256 + k0 + ko);
                #pragma unroll
                for (int ni = 0; ni < 8; ++ni) {
                    bf16x8 bq = ldfrag(kp + (long)(wn + ni * 16 + c0) * 256 + k0 + ko);
                    #pragma unroll
                    for (int mi = 0; mi < 2; ++mi)
                        acc[mi][ni] = __builtin_amdgcn_mfma_f32_16x16x32_bf16(
                            af[mi], bq, acc[mi][ni], 0, 0, 0);
                }
            }

            // ---- mask + div_loss diag + softmax ----
            float rmax[2][4];
            #pragma unroll
            for (int mi = 0; mi < 2; ++mi)
                #pragma unroll
                for (int j = 0; j < 4; ++j) rmax[mi][j] = -3.0e38f;
            #pragma unroll
            for (int mi = 0; mi < 2; ++mi)
                #pragma unroll
                for (int ni = 0; ni < 8; ++ni)
                    #pragma unroll
                    for (int j = 0; j < 4; ++j) {
                        const int rowl = mi * 16 + r0 + j;
                        const int col  = wn + ni * 16 + c0;
                        float s = acc[mi][ni][j];
                        if (col == m0 + rowl)
                            rowpart[(long)b * 512 + m0 + rowl] = 2.f - 2.f * s;
                        bool m = ap[(long)rowl * 512 + col] != 0;
                        s = m ? s : -3.0e38f;
                        acc[mi][ni][j] = s;
                        rmax[mi][j] = fmaxf(rmax[mi][j], s);
                    }
            #pragma unroll
            for (int o = 1; o <= 8; o <<= 1)
                #pragma unroll
                for (int mi = 0; mi < 2; ++mi)
                    #pragma unroll
                    for (int j = 0; j < 4; ++j)
                        rmax[mi][j] = fmaxf(rmax[mi][j], __shfl_xor(rmax[mi][j], o));
            if (c0 == 0) {
                #pragma unroll
                for (int mi = 0; mi < 2; ++mi)
                    #pragma unroll
                    for (int j = 0; j < 4; ++j) redm[mi * 16 + r0 + j][wave] = rmax[mi][j];
            }
            __syncthreads();
            float mx[2][4], rsum[2][4];
            #pragma unroll
            for (int mi = 0; mi < 2; ++mi)
                #pragma unroll
                for (int j = 0; j < 4; ++j) {
                    const int rr = mi * 16 + r0 + j;
                    mx[mi][j] = fmaxf(fmaxf(redm[rr][0], redm[rr][1]),
                                      fmaxf(redm[rr][2], redm[rr][3]));
                    rsum[mi][j] = 0.f;
                }
            #pragma unroll
            for (int mi = 0; mi < 2; ++mi)
                #pragma unroll
                for (int ni = 0; ni < 8; ++ni)
                    #pragma unroll
                    for (int j = 0; j < 4; ++j) {
                        float e = __expf(acc[mi][ni][j] - mx[mi][j]);
                        acc[mi][ni][j] = e;
                        rsum[mi][j] += e;
                    }
            #pragma unroll
            for (int o = 1; o <= 8; o <<= 1)
                #pragma unroll
                for (int mi = 0; mi < 2; ++mi)
                    #pragma unroll
                    for (int j = 0; j < 4; ++j) rsum[mi][j] += __shfl_xor(rsum[mi][j], o);
            if (c0 == 0) {
                #pragma unroll
                for (int mi = 0; mi < 2; ++mi)
                    #pragma unroll
                    for (int j = 0; j < 4; ++j) reds[mi * 16 + r0 + j][wave] = rsum[mi][j];
            }
            __syncthreads();
            float inv[2][4];
            #pragma unroll
            for (int mi = 0; mi < 2; ++mi)
                #pragma unroll
                for (int j = 0; j < 4; ++j) {
                    const int rr = mi * 16 + r0 + j;
                    inv[mi][j] = 1.f / (reds[rr][0] + reds[rr][1] + reds[rr][2] + reds[rr][3]);
                }
            #pragma unroll
            for (int mi = 0; mi < 2; ++mi)
                #pragma unroll
                for (int ni = 0; ni < 8; ++ni)
                    #pragma unroll
                    for (int j = 0; j < 4; ++j) {
                        const int rowl = mi * 16 + r0 + j;
                        const int col  = wn + ni * 16 + c0;
                        float p = acc[mi][ni][j] * inv[mi][j] * dp[(long)rowl * 512 + col];
                        Pls[rowl * 520 + col] = f2b(p);
                    }
        }
        __syncthreads();

        // ---- phase 2: agg[32][256] = P[32,512] @ out[512,256]  (B = outT direct) ----
        f32x4 acc2[2][4] = {};
        {
            const int wn = wave << 6;
            #pragma unroll 2
            for (int k0 = 0; k0 < 512; k0 += 32) {
                bf16x8 af[2];
                #pragma unroll
                for (int mi = 0; mi < 2; ++mi)
                    af[mi] = ldfrag(&Pls[(mi * 16 + c0) * 520 + k0 + ko]);
                #pragma unroll
                for (int ni = 0; ni < 4; ++ni) {
                    bf16x8 bq = ldfrag(ot + (long)(wn + ni * 16 + c0) * 512 + k0 + ko);
                    #pragma unroll
                    for (int mi = 0; mi < 2; ++mi)
                        acc2[mi][ni] = __builtin_amdgcn_mfma_f32_16x16x32_bf16(
                            af[mi], bq, acc2[mi][ni], 0, 0, 0);
                }
            }
        }
        __syncthreads();   // all Pls reads done before T overwrite

        // ---- MLP stage 1: t1 = prelu(agg @ w1)  (B = w1T direct) ----
        const int wn6 = wave << 6;
        const float alphav = av[0];
        #pragma unroll
        for (int mi = 0; mi < 2; ++mi)
            #pragma unroll
            for (int ni = 0; ni < 4; ++ni)
                #pragma unroll
                for (int j = 0; j < 4; ++j)
                    T[(mi * 16 + r0 + j) * 264 + wn6 + ni * 16 + c0] = f2b(acc2[mi][ni][j]);
        __syncthreads();
        f32x4 acct[2][4] = {};
        #pragma unroll 2
        for (int k0 = 0; k0 < 256; k0 += 32) {
            bf16x8 af[2];
            #pragma unroll
            for (int mi = 0; mi < 2; ++mi)
                af[mi] = ldfrag(&T[(mi * 16 + c0) * 264 + k0 + ko]);
            #pragma unroll
            for (int ni = 0; ni < 4; ++ni) {
                bf16x8 bq = ldfrag(w1T + (long)(wn6 + ni * 16 + c0) * 256 + k0 + ko);
                #pragma unroll
                for (int mi = 0; mi < 2; ++mi)
                    acct[mi][ni] = __builtin_amdgcn_mfma_f32_16x16x32_bf16(
                        af[mi], bq, acct[mi][ni], 0, 0, 0);
            }
        }
        __syncthreads();
        #pragma unroll
        for (int mi = 0; mi < 2; ++mi)
            #pragma unroll
            for (int ni = 0; ni < 4; ++ni)
                #pragma unroll
                for (int j = 0; j < 4; ++j) {
                    float x = acct[mi][ni][j];
                    x = (x >= 0.f) ? x : alphav * x;
                    T[(mi * 16 + r0 + j) * 264 + wn6 + ni * 16 + c0] = f2b(x);
                }
        __syncthreads();

        // ---- MLP stage 2: h1 = prelu(t1 @ w2 + bias)  (B = w2T direct) ----
        f32x4 acc3[2][4] = {};
        #pragma unroll 2
        for (int k0 = 0; k0 < 256; k0 += 32) {
            bf16x8 af[2];
            #pragma unroll
            for (int mi = 0; mi < 2; ++mi)
                af[mi] = ldfrag(&T[(mi * 16 + c0) * 264 + k0 + ko]);
            #pragma unroll
            for (int ni = 0; ni < 4; ++ni) {
                bf16x8 bq = ldfrag(w2T + (long)(wn6 + ni * 16 + c0) * 256 + k0 + ko);
                #pragma unroll
                for (int mi = 0; mi < 2; ++mi)
                    acc3[mi][ni] = __builtin_amdgcn_mfma_f32_16x16x32_bf16(
                        af[mi], bq, acc3[mi][ni], 0, 0, 0);
            }
        }

        // ---- epilogue: bias + prelu + row l2norm + psum + n1 ----
        const float alpha1 = a1[0];
        float rs[2][4] = {};
        #pragma unroll
        for (int ni = 0; ni < 4; ++ni) {
            const float bv = bias1[wn6 + ni * 16 + c0];
            #pragma unroll
            for (int mi = 0; mi < 2; ++mi)
                #pragma unroll
                for (int j = 0; j < 4; ++j) {
                    float x = acc3[mi][ni][j] + bv;
                    x = (x >= 0.f) ? x : alpha1 * x;
                    acc3[mi][ni][j] = x;
                    rs[mi][j] += x * x;
                }
        }
        #pragma unroll
        for (int o = 1; o <= 8; o <<= 1)
            #pragma unroll
            for (int mi = 0; mi < 2; ++mi)
                #pragma unroll
                for (int j = 0; j < 4; ++j) rs[mi][j] += __shfl_xor(rs[mi][j], o);
        __syncthreads();   // T reads done
        if (c0 == 0) {
            #pragma unroll
            for (int mi = 0; mi < 2; ++mi)
                #pragma unroll
                for (int j = 0; j < 4; ++j) redm[mi * 16 + r0 + j][wave] = rs[mi][j];
        }
        __syncthreads();
        float inv2[2][4];
        #pragma unroll
        for (int mi = 0; mi < 2; ++mi)
            #pragma unroll
            for (int j = 0; j < 4; ++j) {
                const int rr = mi * 16 + r0 + j;
                float s = redm[rr][0] + redm[rr][1] + redm[rr][2] + redm[rr][3];
                inv2[mi][j] = 1.f / fmaxf(sqrtf(s), 1e-12f);
            }
        float cs[4];
        #pragma unroll
        for (int ni = 0; ni < 4; ++ni) {
            float s = 0.f;
            #pragma unroll
            for (int mi = 0; mi < 2; ++mi)
                #pragma unroll
                for (int j = 0; j < 4; ++j) s += acc3[mi][ni][j];
            s += __shfl_xor(s, 16);
            s += __shfl_xor(s, 32);
            cs[ni] = s;
        }
        if (lane < 16) {
            #pragma unroll
            for (int ni = 0; ni < 4; ++ni)
                psum1[(long)idx * 256 + wn6 + ni * 16 + lane] = cs[ni];
        }
        const long row0g = (long)b * 512 + m0;
        #pragma unroll
        for (int mi = 0; mi < 2; ++mi)
            #pragma unroll
            for (int ni = 0; ni < 4; ++ni)
                #pragma unroll
                for (int j = 0; j < 4; ++j)
                    n1[(row0g + mi * 16 + r0 + j) * 256 + wn6 + ni * 16 + c0] =
                        f2b(acc3[mi][ni][j] * inv2[mi][j]);
    } else {
        // ================= h2 branch role (diff GEMM + norm, all direct) =================
        const int z = idx >> 4;           // batch
        const int arow0 = (idx & 15) << 5;
        const unsigned short* ad = diff_bf + (long)z * 262144;
        const unsigned short* bt = fts2T + z * 512;
        const int wn = wave << 6;

        f32x4 acc[2][4] = {};
        #pragma unroll 2
        for (int k0 = 0; k0 < 512; k0 += 32) {
            bf16x8 af[2];
            #pragma unroll
            for (int mi = 0; mi < 2; ++mi)
                af[mi] = ldfrag(ad + (long)(arow0 + mi * 16 + c0) * 512 + k0 + ko);
            #pragma unroll
            for (int ni = 0; ni < 4; ++ni) {
                bf16x8 bq = ldfrag(bt + (long)(wn + ni * 16 + c0) * 8192 + k0 + ko);
                #pragma unroll
                for (int mi = 0; mi < 2; ++mi)
                    acc[mi][ni] = __builtin_amdgcn_mfma_f32_16x16x32_bf16(
                        af[mi], bq, acc[mi][ni], 0, 0, 0);
            }
        }

        const float alpha = a2[0];
        float rs[2][4] = {};
        #pragma unroll
        for (int ni = 0; ni < 4; ++ni) {
            const float bv = bias2[wn + ni * 16 + c0];
            #pragma unroll
            for (int mi = 0; mi < 2; ++mi)
                #pragma unroll
                for (int j = 0; j < 4; ++j) {
                    float x = acc[mi][ni][j] + bv;
                    x = (x >= 0.f) ? x : alpha * x;
                    acc[mi][ni][j] = x;
                    rs[mi][j] += x * x;
                }
        }
        #pragma unroll
        for (int o = 1; o <= 8; o <<= 1)
            #pragma unroll
            for (int mi = 0; mi < 2; ++mi)
                #pragma unroll
                for (int j = 0; j < 4; ++j) rs[mi][j] += __shfl_xor(rs[mi][j], o);
        if (c0 == 0) {
            #pragma unroll
            for (int mi = 0; mi < 2; ++mi)
                #pragma unroll
                for (int j = 0; j < 4; ++j) redm[mi * 16 + r0 + j][wave] = rs[mi][j];
        }
        __syncthreads();
        float inv[2][4];
        #pragma unroll
        for (int mi = 0; mi < 2; ++mi)
            #pragma unroll
            for (int j = 0; j < 4; ++j) {
                const int rr = mi * 16 + r0 + j;
                float s = redm[rr][0] + redm[rr][1] + redm[rr][2] + redm[rr][3];
                inv[mi][j] = 1.f / fmaxf(sqrtf(s), 1e-12f);
            }
        float cs[4];
        #pragma unroll
        for (int ni = 0; ni < 4; ++ni) {
            float s = 0.f;
            #pragma unroll
            for (int mi = 0; mi < 2; ++mi)
                #pragma unroll
                for (int j = 0; j < 4; ++j) s += acc[mi][ni][j];
            s += __shfl_xor(s, 16);
            s += __shfl_xor(s, 32);
            cs[ni] = s;
        }
        if (lane < 16) {
            #pragma unroll
            for (int ni = 0; ni < 4; ++ni)
                psum2[(long)idx * 256 + wn + ni * 16 + lane] = cs[ni];
        }
        const long grow0 = (long)idx * 32;
        #pragma unroll
        for (int mi = 0; mi < 2; ++mi)
            #pragma unroll
            for (int ni = 0; ni < 4; ++ni)
                #pragma unroll
                for (int j = 0; j < 4; ++j)
                    n2[(grow0 + mi * 16 + r0 + j) * 256 + wn + ni * 16 + c0] =
                        f2b(acc[mi][ni][j] * inv[mi][j]);
    }
}

// ---------------------------------------------------------------------------
// Workspace layout (bytes). End = 49,872,896 (~47.6 MB).
// ---------------------------------------------------------------------------
static constexpr long OFF_SEQ_BF  = 0;                  // [8192,128] bf16, 2MB
static constexpr long OFF_FC1T    = 2097152;            // [2][256][128]
static constexpr long OFF_QWT     = 2228224;            // [512][256] stacked q|k
static constexpr long OFF_VW1T    = 2490368;
static constexpr long OFF_VW2T    = 2621440;
static constexpr long OFF_ADJ     = 3145728;            // 8MB
static constexpr long OFF_DIFF    = 11534336;           // 8MB
static constexpr long OFF_FTST    = 19922944;           // [2][256][8192] 8MB
static constexpr long OFF_OUTT    = 28311552;           // [16][256][512] 4MB
static constexpr long OFF_QBF     = 32505856;           // 4MB
static constexpr long OFF_KBF     = 36700160;           // 4MB
static constexpr long OFF_N1      = 40894464;           // 4MB
static constexpr long OFF_N2      = 45088768;           // 4MB
static constexpr long OFF_PSUM    = 49283072;           // 2x 256KB
static constexpr long OFF_ROWPART = 49807360;           // 32KB

extern "C" void kernel_launch(void* const* d_in, const int* in_sizes, int n_in,
                              void* d_out, int out_size, void* d_ws, size_t ws_size,
                              hipStream_t stream) {
    const float* seq      = (const float*)d_in[0];
    const float* adj      = (const float*)d_in[1];
    const float* diff     = (const float*)d_in[2];
    const float* drop     = (const float*)d_in[3];
    const float* fc1_w    = (const float*)d_in[4];
    const float* q_w      = (const float*)d_in[5];
    const float* k_w      = (const float*)d_in[6];
    const float* v_w1     = (const float*)d_in[7];
    const float* v_w2     = (const float*)d_in[8];
    const float* fc2_w    = (const float*)d_in[9];
    const float* bias1    = (const float*)d_in[10];
    const float* bias2    = (const float*)d_in[11];
    const float* prelu1_a = (const float*)d_in[12];
    const float* prelu2_a = (const float*)d_in[13];
    const float* v_prelu  = (const float*)d_in[14];
    float* out = (float*)d_out;

    char* ws = (char*)d_ws;
    unsigned short* seq_bf  = (unsigned short*)(ws + OFF_SEQ_BF);
    unsigned short* fc1T    = (unsigned short*)(ws + OFF_FC1T);
    unsigned short* fc2T    = (unsigned short*)(ws + OFF_FC1T + 65536);
    unsigned short* qwT     = (unsigned short*)(ws + OFF_QWT);
    unsigned short* kwT     = (unsigned short*)(ws + OFF_QWT + 131072);
    unsigned short* vw1T    = (unsigned short*)(ws + OFF_VW1T);
    unsigned short* vw2T    = (unsigned short*)(ws + OFF_VW2T);
    unsigned short* adj_bf  = (unsigned short*)(ws + OFF_ADJ);
    unsigned short* diff_bf = (unsigned short*)(ws + OFF_DIFF);
    unsigned short* ftsT    = (unsigned short*)(ws + OFF_FTST);
    unsigned short* fts2T   = (unsigned short*)(ws + OFF_FTST + 4194304);
    unsigned short* outT    = (unsigned short*)(ws + OFF_OUTT);
    unsigned short* q_bf    = (unsigned short*)(ws + OFF_QBF);
    unsigned short* k_bf    = (unsigned short*)(ws + OFF_KBF);
    unsigned short* n1_bf   = (unsigned short*)(ws + OFF_N1);
    unsigned short* n2_bf   = (unsigned short*)(ws + OFF_N2);
    float*          psum1   = (float*)(ws + OFF_PSUM);
    float*          psum2   = (float*)(ws + OFF_PSUM + 262144);
    float*          rowpart = (float*)(ws + OFF_ROWPART);

    // 1: conversions + weight transposes
    prep<<<9600, 256, 0, stream>>>(seq, adj, diff, fc1_w, fc2_w, q_w, k_w, v_w1, v_w2,
                                   seq_bf, adj_bf, diff_bf, fc1T, fc2T, qwT, kwT, vw1T, vw2T);

    // 2: ftsT|fts2T = [fc1|fc2]^T @ seq^T  (batched z=2, LDS-staged)
    gemm_nt<64, false, true, false, false><<<dim3(64, 4, 2), 256, 0, stream>>>(
        fc1T, seq_bf, nullptr, ftsT,
        256, 8192, 128, 128, 128, 8192, 32768, 0, 2097152,
        nullptr, nullptr, nullptr, nullptr, nullptr);

    // 3: out = adj@fts -> outT (+LDS Ot), then qk proj + l2norm  (direct frags)
    gcn1qk<<<dim3(32, 16), 256, 0, stream>>>(adj_bf, ftsT, qwT, outT, q_bf, k_bf);

    // 4: merged attention+MLP | h2 branch  (direct frags)
    attmlp_h2<<<512, 256, 0, stream>>>(
        q_bf, k_bf, adj_bf, drop, outT, vw1T, vw2T, bias1, v_prelu, prelu1_a,
        n1_bf, psum1, rowpart,
        diff_bf, fts2T, bias2, prelu2_a, n2_bf, psum2);

    // 5: node_logits GEMM + fused readout in block (0,0)
    gemm_nt<128, true, false, true, true><<<dim3(64, 64, 1), 256, 0, stream>>>(
        n1_bf, n2_bf, out, nullptr,
        8192, 8192, 256, 256, 256, 8192, 0, 0, 0,
        psum1, psum2, rowpart, out + 67108864, out + 67109120);

    (void)in_sizes; (void)n_in; (void)out_size; (void)ws_size;
}